// Round 4
// baseline (107.811 us; speedup 1.0000x reference)
//
#include <hip/hip_runtime.h>

// ---------------------------------------------------------------------------
// KAN forward as one bf16 MFMA GEMM:
//   y[n,o] = sum_i ( silu(x[n,i])*scale_base[o,i]
//                  + sum_b basis_b(x[n,i]) * scale_sp[o,i]*coef[o,i,b] ) + bias[o]
// A[n, i*8+s], W[o, i*8+s]: s=0 -> (silu, scale_base); s=1..6 -> (basis, sp*coef);
// s=7 -> zero pad.  K = 512*8 = 4096.
// Round 4: BM=64/BN=256, 256 threads, LDS 80KB -> 2 independent blocks/CU so
// one block's kan_act VALU overlaps the other's MFMA. v_cvt_pk_bf16_f32 for
// the bf16 convert+pack (4 ops instead of ~36).
// ---------------------------------------------------------------------------

typedef short        bf16x8 __attribute__((ext_vector_type(8)));
typedef float        f32x4  __attribute__((ext_vector_type(4)));
typedef unsigned int u32x4  __attribute__((ext_vector_type(4)));

#define NROWS 16384
#define DIN   512
#define DOUT  512
#define BM    64
#define BN    256
#define NKT   64              // K-steps; each covers 8 input features (64 k-units)
#define WT_TILE_BYTES 32768   // 256 rows x 64 bf16 (128B rows)

__device__ __forceinline__ unsigned short f2bf(float f) {
    unsigned int u = __float_as_uint(f);
    u += 0x7fffu + ((u >> 16) & 1u);          // round-to-nearest-even
    return (unsigned short)(u >> 16);
}

// activation vector for one x value: [silu, basis0..5, 0] packed as 4 u32
// (8 bf16) via hardware v_cvt_pk_bf16_f32.
__device__ __forceinline__ u32x4 kan_act_pk(float xv) {
    float S = (xv + 3.0f) * 1.5f;             // knot-space coordinate, cells [m, m+1)
    float r[10];
#pragma unroll
    for (int m = 0; m < 10; ++m) {
        float t = fmaxf(S - (float)m, 0.0f);  // truncated power basis
        r[m] = t * t * t;
    }
    float sc = (S < 9.0f) ? (1.0f / 6.0f) : 0.0f;  // x>=3 -> basis zero; S<0 -> r==0
    float e  = __expf(-xv);
    float si = xv / (1.0f + e);               // silu
    float b[6];
#pragma unroll
    for (int j = 0; j < 6; ++j)
        b[j] = (r[j] - 4.0f * r[j+1] + 6.0f * r[j+2] - 4.0f * r[j+3] + r[j+4]) * sc;
    u32x4 o;
    asm("v_cvt_pk_bf16_f32 %0, %1, %2" : "=v"(o[0]) : "v"(si),   "v"(b[0]));
    asm("v_cvt_pk_bf16_f32 %0, %1, %2" : "=v"(o[1]) : "v"(b[1]), "v"(b[2]));
    asm("v_cvt_pk_bf16_f32 %0, %1, %2" : "=v"(o[2]) : "v"(b[3]), "v"(b[4]));
    asm("v_cvt_pk_bf16_f32 %0, %1, 0"  : "=v"(o[3]) : "v"(b[5]));
    return o;
}

// ---------------------------------------------------------------------------
// Prep: pack W into ws as bf16, tiled per (ntile, kstep) in the exact LDS image
// (pre-XOR-swizzled) so GEMM can global_load_lds it linearly.
//   tile(nt,kt): 256 rows (o_local) x 128 bytes; element (ol, colbyte):
//   byte = ol*128 + (colbyte ^ ((ol&7)<<4))
// ---------------------------------------------------------------------------
__global__ __launch_bounds__(256) void kan_prep(
    const float* __restrict__ coef, const float* __restrict__ scale_base,
    const float* __restrict__ scale_sp, unsigned short* __restrict__ wt)
{
    int t = blockIdx.x * 256 + threadIdx.x;   // (o,i) pair, 0..262143
    int o = t >> 9;
    int i = t & 511;
    float sb = scale_base[t];
    float sp = scale_sp[t];
    const float* cp = coef + (size_t)t * 6;
    bf16x8 w;
    w[0] = (short)f2bf(sb);
#pragma unroll
    for (int b = 0; b < 6; ++b) w[1 + b] = (short)f2bf(sp * cp[b]);
    w[7] = 0;
    int nt = o >> 8;
    int ol = o & 255;
    int kt = i >> 3;
    int colbyte = (i & 7) << 4;               // 16 bytes per feature (8 bf16 slots)
    unsigned off = (unsigned)((nt * NKT + kt) * WT_TILE_BYTES
                              + ol * 128 + (colbyte ^ ((ol & 7) << 4)));
    *(bf16x8*)((char*)wt + off) = w;
}

__device__ __forceinline__ void gload_lds16(const void* g, void* l) {
    __builtin_amdgcn_global_load_lds(
        (const __attribute__((address_space(1))) void*)g,
        (__attribute__((address_space(3))) void*)l, 16, 0, 0);
}

// ---------------------------------------------------------------------------
// Fused GEMM: BM=64 x BN=256, BK=64 k-units (8 features), 256 threads (4 waves
// 1x4), wave tile 64x64 (4x4 fragments), mfma_f32_16x16x32_bf16.
// LDS 80KB double-buffered -> 2 blocks/CU, cross-block VALU/MFMA overlap.
// ---------------------------------------------------------------------------
__global__ __launch_bounds__(256, 2) void kan_gemm(
    const float* __restrict__ x, const unsigned short* __restrict__ wt,
    const float* __restrict__ bias, float* __restrict__ y)
{
    __shared__ char As[2][BM * 128];   // 2 x  8 KB, swizzled rows of 64 bf16
    __shared__ char Ws[2][BN * 128];   // 2 x 32 KB

    const int tid  = threadIdx.x;
    const int lane = tid & 63;
    const int wid  = tid >> 6;        // 0..3

    // bijective XCD-aware swizzle: 512 wgs, 8 XCDs, contiguous 64-chunk each.
    // XCDs 0-3 -> nt=0, XCDs 4-7 -> nt=1: 2MB W-half stays L2-resident per XCD.
    int bid = blockIdx.x;
    int wg  = (bid & 7) * 64 + (bid >> 3);
    int mt  = wg & 255;
    int nt  = wg >> 8;

    const int row0 = mt * BM;
    const int col0 = nt * BN;

    // A staging: thread -> (row ar, feature-pair ap); loads float2 of x
    const int ar = tid >> 2;          // 0..63
    const int ap = tid & 3;           // 0..3
    const float* xp = x + (size_t)(row0 + ar) * DIN + ap * 2;
    const int as_sw = (ar & 7) << 4;
    const int c0 = (ap * 2) << 4;

    const char* wsrc = (const char*)wt + (size_t)nt * NKT * WT_TILE_BYTES;

    f32x4 acc[4][4];
#pragma unroll
    for (int m2 = 0; m2 < 4; ++m2)
#pragma unroll
        for (int n2 = 0; n2 < 4; ++n2) {
            f32x4 z = {0.f, 0.f, 0.f, 0.f};
            acc[m2][n2] = z;
        }

    const int fr = lane & 15;         // fragment row/col
    const int fg = lane >> 4;         // k-group 0..3

    // ---------------- prologue: stage buffer 0 for kt=0 ----------------
    {
        const char* s = wsrc + wid * 1024 + lane * 16;
        char* d = &Ws[0][wid * 1024];
#pragma unroll
        for (int q = 0; q < 8; ++q)
            gload_lds16(s + q * 4096, d + q * 4096);
        float2 xa = *(const float2*)(xp);
        u32x4 a0 = kan_act_pk(xa.x);
        u32x4 a1 = kan_act_pk(xa.y);
        char* rowp = &As[0][ar * 128];
        *(u32x4*)(rowp + (c0 ^ as_sw))        = a0;
        *(u32x4*)(rowp + ((c0 + 16) ^ as_sw)) = a1;
    }
    float2 xb = *(const float2*)(xp + 8);   // x for kt=1
    asm volatile("s_waitcnt vmcnt(0) lgkmcnt(0)" ::: "memory");
    __builtin_amdgcn_s_barrier();

    // ---------------- main loop ----------------
    int cur = 0;
    for (int kt = 0; kt < NKT; ++kt) {
        const int nxt = cur ^ 1;
        const bool has_next = (kt + 1 < NKT);

        if (has_next) {
            // issue next W tile loads (latency hides under this + other block's MFMA)
            const char* s = wsrc + (kt + 1) * WT_TILE_BYTES + wid * 1024 + lane * 16;
            char* d = &Ws[nxt][wid * 1024];
#pragma unroll
            for (int q = 0; q < 8; ++q)
                gload_lds16(s + q * 4096, d + q * 4096);
            // compute next A activations (VALU overlaps other block's MFMA)
            u32x4 a0 = kan_act_pk(xb.x);
            u32x4 a1 = kan_act_pk(xb.y);
            char* rowp = &As[nxt][ar * 128];
            *(u32x4*)(rowp + (c0 ^ as_sw))        = a0;
            *(u32x4*)(rowp + ((c0 + 16) ^ as_sw)) = a1;
            if (kt + 2 < NKT)
                xb = *(const float2*)(xp + (kt + 2) * 8);
        }

        // ---- compute on buf[cur]: BK=64 as two k-slices of 32
#pragma unroll
        for (int ks = 0; ks < 2; ++ks) {
            const int cb = ks * 64 + fg * 16;   // byte col within row
            bf16x8 af[4], bf[4];
#pragma unroll
            for (int m2 = 0; m2 < 4; ++m2) {
                int rr = m2 * 16 + fr;
                af[m2] = *(const bf16x8*)(&As[cur][0] + rr * 128 + (cb ^ ((rr & 7) << 4)));
            }
#pragma unroll
            for (int n2 = 0; n2 < 4; ++n2) {
                int wr = wid * 64 + n2 * 16 + fr;
                bf[n2] = *(const bf16x8*)(&Ws[cur][0] + wr * 128 + (cb ^ ((wr & 7) << 4)));
            }
            __builtin_amdgcn_s_setprio(1);
#pragma unroll
            for (int m2 = 0; m2 < 4; ++m2)
#pragma unroll
                for (int n2 = 0; n2 < 4; ++n2)
                    acc[m2][n2] = __builtin_amdgcn_mfma_f32_16x16x32_bf16(
                        af[m2], bf[n2], acc[m2][n2], 0, 0, 0);
            __builtin_amdgcn_s_setprio(0);
        }

        if (has_next) {
            asm volatile("s_waitcnt vmcnt(0) lgkmcnt(0)" ::: "memory");
            __builtin_amdgcn_s_barrier();
        }
        cur = nxt;
    }

    // ---- epilogue: C/D layout col = lane&15, row = (lane>>4)*4 + reg
    const int orow0 = row0 + fg * 4;
    const int ocol0 = col0 + wid * 64 + fr;
#pragma unroll
    for (int n2 = 0; n2 < 4; ++n2) {
        float bv = bias[ocol0 + n2 * 16];
#pragma unroll
        for (int m2 = 0; m2 < 4; ++m2) {
#pragma unroll
            for (int r = 0; r < 4; ++r) {
                y[(size_t)(orow0 + m2 * 16 + r) * DOUT + (ocol0 + n2 * 16)]
                    = acc[m2][n2][r] + bv;
            }
        }
    }
}

extern "C" void kernel_launch(void* const* d_in, const int* in_sizes, int n_in,
                              void* d_out, int out_size, void* d_ws, size_t ws_size,
                              hipStream_t stream)
{
    const float* x          = (const float*)d_in[0];
    const float* coef       = (const float*)d_in[1];
    const float* scale_base = (const float*)d_in[2];
    const float* scale_sp   = (const float*)d_in[3];
    const float* bias       = (const float*)d_in[4];
    unsigned short* wt = (unsigned short*)d_ws;   // 4 MB (2 ntiles * 64 kt * 32 KB)
    float* y = (float*)d_out;

    kan_prep<<<1024, 256, 0, stream>>>(coef, scale_base, scale_sp, wt);
    kan_gemm<<<512, 256, 0, stream>>>(x, wt, bias, y);
}

// Round 5
// 96.139 us; speedup vs baseline: 1.1214x; 1.1214x over previous
//
#include <hip/hip_runtime.h>

// ---------------------------------------------------------------------------
// KAN forward as one bf16 MFMA GEMM:
//   y[n,o] = sum_i ( silu(x[n,i])*scale_base[o,i]
//                  + sum_b basis_b(x[n,i]) * scale_sp[o,i]*coef[o,i,b] ) + bias[o]
// A[n, i*8+s], W[o, i*8+s]: s=0 -> (silu, scale_base); s=1..6 -> (basis, sp*coef);
// s=7 -> zero pad.  K = 512*8 = 4096.
// Round 5: lean cell-local B-spline eval with slot-scatter (invalid splines ->
// pad slot 7 which meets W=0), counted vmcnt (no per-iter full drain),
// ds_reads hoisted above act-VALU so the compiler can interleave with MFMA.
// ---------------------------------------------------------------------------

typedef short        bf16x8 __attribute__((ext_vector_type(8)));
typedef float        f32x4  __attribute__((ext_vector_type(4)));
typedef unsigned int u32x4  __attribute__((ext_vector_type(4)));

#define NROWS 16384
#define DIN   512
#define DOUT  512
#define BM    64
#define BN    256
#define NKT   64              // K-steps; each covers 8 input features (64 k-units)
#define WT_TILE_BYTES 32768   // 256 rows x 64 bf16 (128B rows)

__device__ __forceinline__ unsigned short f2bf(float f) {
    unsigned int u = __float_as_uint(f);
    u += 0x7fffu + ((u >> 16) & 1u);          // round-to-nearest-even
    return (unsigned short)(u >> 16);
}

// ---------------------------------------------------------------------------
// Lean activation store: one feature's 8-slot group at p16 (16B, swizzle
// already applied; bytes within the group are contiguous since the XOR
// swizzle only touches bits 4..6 of the byte address).
//   slot 0 = silu(x); slots 1..6 = basis_{0..5}(x); slot 7 = pad (W==0).
// Cell-local eval: S = 1.5x+4.5, j = floor(S), t = S-j in [0,1).
// Nonzero splines: basis_{j-3+m} = n_m(t), m=0..3. Out-of-range -> slot 7.
// ---------------------------------------------------------------------------
__device__ __forceinline__ void kan_act_store(float xv, char* p16) {
    float S  = __builtin_fmaf(xv, 1.5f, 4.5f);
    float jf = floorf(S);
    float t  = S - jf;
    int   j  = (int)jf;
    float t2 = t * t;
    float t3 = t2 * t;
    float omt  = 1.0f - t;
    float omt2 = omt * omt;
    float n0 = omt2 * omt * (1.0f / 6.0f);                    // (1-t)^3/6
    float n1 = __builtin_fmaf(t3, 0.5f, -t2) + (2.0f / 3.0f); // (3t^3-6t^2+4)/6
    float u  = (t + t2) - t3;
    float n2 = __builtin_fmaf(u, 0.5f, 1.0f / 6.0f);          // (-3t^3+3t^2+3t+1)/6
    float n3 = t3 * (1.0f / 6.0f);                            // t^3/6
    float e  = __expf(-xv);
    float si = xv * __builtin_amdgcn_rcpf(1.0f + e);          // silu

    unsigned w01, w23, wsil;
    asm("v_cvt_pk_bf16_f32 %0, %1, %2" : "=v"(w01)  : "v"(n0), "v"(n1));
    asm("v_cvt_pk_bf16_f32 %0, %1, %2" : "=v"(w23)  : "v"(n2), "v"(n3));
    asm("v_cvt_pk_bf16_f32 %0, %1, %2" : "=v"(wsil) : "v"(si), "v"(0.0f));

    u32x4 init = {wsil, 0u, 0u, 0u};   // [silu, 0,0,0,0,0,0,0]
    *(u32x4*)p16 = init;

    unsigned short v0 = (unsigned short)w01, v1 = (unsigned short)(w01 >> 16);
    unsigned short v2 = (unsigned short)w23, v3 = (unsigned short)(w23 >> 16);
    int b0 = j - 3;
    int s0 = ((unsigned)(b0    ) <= 5u) ? (b0 + 1) : 7;
    int s1 = ((unsigned)(b0 + 1) <= 5u) ? (b0 + 2) : 7;
    int s2 = ((unsigned)(b0 + 2) <= 5u) ? (b0 + 3) : 7;
    int s3 = ((unsigned)(b0 + 3) <= 5u) ? (b0 + 4) : 7;
    // program order: later writes win; ascending m so valid slots never get
    // clobbered (collisions only happen at slot 7 = pad).
    *(unsigned short*)(p16 + 2 * s0) = v0;
    *(unsigned short*)(p16 + 2 * s1) = v1;
    *(unsigned short*)(p16 + 2 * s2) = v2;
    *(unsigned short*)(p16 + 2 * s3) = v3;
}

// ---------------------------------------------------------------------------
// Prep: pack W into ws as bf16, tiled per (ntile, kstep) in the exact LDS image
// (pre-XOR-swizzled) so GEMM can global_load_lds it linearly.
// ---------------------------------------------------------------------------
__global__ __launch_bounds__(256) void kan_prep(
    const float* __restrict__ coef, const float* __restrict__ scale_base,
    const float* __restrict__ scale_sp, unsigned short* __restrict__ wt)
{
    int t = blockIdx.x * 256 + threadIdx.x;   // (o,i) pair, 0..262143
    int o = t >> 9;
    int i = t & 511;
    float sb = scale_base[t];
    float sp = scale_sp[t];
    const float* cp = coef + (size_t)t * 6;
    bf16x8 w;
    w[0] = (short)f2bf(sb);
#pragma unroll
    for (int b = 0; b < 6; ++b) w[1 + b] = (short)f2bf(sp * cp[b]);
    w[7] = 0;
    int nt = o >> 8;
    int ol = o & 255;
    int kt = i >> 3;
    int colbyte = (i & 7) << 4;               // 16 bytes per feature (8 bf16 slots)
    unsigned off = (unsigned)((nt * NKT + kt) * WT_TILE_BYTES
                              + ol * 128 + (colbyte ^ ((ol & 7) << 4)));
    *(bf16x8*)((char*)wt + off) = w;
}

__device__ __forceinline__ void gload_lds16(const void* g, void* l) {
    __builtin_amdgcn_global_load_lds(
        (const __attribute__((address_space(1))) void*)g,
        (__attribute__((address_space(3))) void*)l, 16, 0, 0);
}

// ---------------------------------------------------------------------------
// Fused GEMM: BM=64 x BN=256, BK=64 k-units (8 features), 256 threads (4 waves
// 1x4), wave tile 64x64 (4x4 frags), mfma_f32_16x16x32_bf16.
// Double-buffered; per iter: issue G(kt+1) -> vmcnt(9) -> ds_read frags(kt)
// -> acts(kt+1) -> MFMA(kt) -> lgkmcnt(0) -> s_barrier.  W loads stay in
// flight across the barrier (counted vmcnt, never 0 in steady state).
// ---------------------------------------------------------------------------
__global__ __launch_bounds__(256, 2) void kan_gemm(
    const float* __restrict__ x, const unsigned short* __restrict__ wt,
    const float* __restrict__ bias, float* __restrict__ y)
{
    __shared__ char As[2][BM * 128];   // 2 x  8 KB
    __shared__ char Ws[2][BN * 128];   // 2 x 32 KB

    const int tid  = threadIdx.x;
    const int lane = tid & 63;
    const int wid  = tid >> 6;        // 0..3

    // bijective XCD-aware swizzle: 512 wgs, 8 XCDs, contiguous 64-chunk each.
    int bid = blockIdx.x;
    int wg  = (bid & 7) * 64 + (bid >> 3);
    int mt  = wg & 255;
    int nt  = wg >> 8;

    const int row0 = mt * BM;
    const int col0 = nt * BN;

    // A staging: thread -> (row ar, feature-pair ap)
    const int ar = tid >> 2;          // 0..63
    const int ap = tid & 3;           // 0..3
    const float* xp = x + (size_t)(row0 + ar) * DIN + ap * 2;
    const int as_sw = (ar & 7) << 4;
    const int c0 = (ap * 2) << 4;

    const char* wsrc = (const char*)wt + (size_t)nt * NKT * WT_TILE_BYTES;

    f32x4 acc[4][4];
#pragma unroll
    for (int m2 = 0; m2 < 4; ++m2)
#pragma unroll
        for (int n2 = 0; n2 < 4; ++n2) {
            f32x4 z = {0.f, 0.f, 0.f, 0.f};
            acc[m2][n2] = z;
        }

    const int fr = lane & 15;         // fragment row/col
    const int fg = lane >> 4;         // k-group 0..3

    // ---------------- prologue: stage buffer 0 for kt=0 ----------------
    float2 xa = *(const float2*)(xp);         // X(0)
    {
        const char* s = wsrc + wid * 1024 + lane * 16;
        char* d = &Ws[0][wid * 1024];
#pragma unroll
        for (int q = 0; q < 8; ++q)
            gload_lds16(s + q * 4096, d + q * 4096);
        char* rowp = &As[0][ar * 128];
        kan_act_store(xa.x, rowp + (c0 ^ as_sw));
        kan_act_store(xa.y, rowp + ((c0 + 16) ^ as_sw));
    }
    float2 xb = *(const float2*)(xp + 8);     // X(1)
    asm volatile("s_waitcnt lgkmcnt(0)" ::: "memory");
    __builtin_amdgcn_s_barrier();

    // ---------------- main loop ----------------
    int cur = 0;
    for (int kt = 0; kt < NKT; ++kt) {
        const int nxt = cur ^ 1;
        const bool has_next = (kt + 1 < NKT);

        if (has_next) {
            // issue next W tile loads; they stay in flight through this iter
            const char* s = wsrc + (kt + 1) * WT_TILE_BYTES + wid * 1024 + lane * 16;
            char* d = &Ws[nxt][wid * 1024];
#pragma unroll
            for (int q = 0; q < 8; ++q)
                gload_lds16(s + q * 4096, d + q * 4096);
            // counted wait: allow the 8 just-issued + 1 x-prefetch in flight;
            // guarantees W(kt) (issued last iter) has landed in Ws[cur].
            asm volatile("s_waitcnt vmcnt(9)" ::: "memory");
        } else {
            asm volatile("s_waitcnt vmcnt(0)" ::: "memory");
        }

        // ---- issue all fragment reads for kt (latency hides under acts)
        bf16x8 af[2][4], bf[2][4];
#pragma unroll
        for (int ks = 0; ks < 2; ++ks) {
            const int cb = ks * 64 + fg * 16;
#pragma unroll
            for (int m2 = 0; m2 < 4; ++m2) {
                int rr = m2 * 16 + fr;
                af[ks][m2] = *(const bf16x8*)(&As[cur][0] + rr * 128 + (cb ^ ((rr & 7) << 4)));
            }
#pragma unroll
            for (int n2 = 0; n2 < 4; ++n2) {
                int wr = wid * 64 + n2 * 16 + fr;
                bf[ks][n2] = *(const bf16x8*)(&Ws[cur][0] + wr * 128 + (cb ^ ((wr & 7) << 4)));
            }
        }

        if (has_next) {
            // compute next A activations (VALU; compiler may interleave with MFMA)
            char* rowp = &As[nxt][ar * 128];
            kan_act_store(xb.x, rowp + (c0 ^ as_sw));
            kan_act_store(xb.y, rowp + ((c0 + 16) ^ as_sw));
            if (kt + 2 < NKT)
                xb = *(const float2*)(xp + (kt + 2) * 8);
        }

        // ---- MFMA on kt
#pragma unroll
        for (int ks = 0; ks < 2; ++ks)
#pragma unroll
            for (int m2 = 0; m2 < 4; ++m2)
#pragma unroll
                for (int n2 = 0; n2 < 4; ++n2)
                    acc[m2][n2] = __builtin_amdgcn_mfma_f32_16x16x32_bf16(
                        af[ks][m2], bf[ks][n2], acc[m2][n2], 0, 0, 0);

        asm volatile("s_waitcnt lgkmcnt(0)" ::: "memory");
        __builtin_amdgcn_s_barrier();
        cur = nxt;
    }

    // ---- epilogue: C/D layout col = lane&15, row = (lane>>4)*4 + reg
    const int orow0 = row0 + fg * 4;
    const int ocol0 = col0 + wid * 64 + fr;
#pragma unroll
    for (int n2 = 0; n2 < 4; ++n2) {
        float bv = bias[ocol0 + n2 * 16];
#pragma unroll
        for (int m2 = 0; m2 < 4; ++m2) {
#pragma unroll
            for (int r = 0; r < 4; ++r) {
                y[(size_t)(orow0 + m2 * 16 + r) * DOUT + (ocol0 + n2 * 16)]
                    = acc[m2][n2][r] + bv;
            }
        }
    }
}

extern "C" void kernel_launch(void* const* d_in, const int* in_sizes, int n_in,
                              void* d_out, int out_size, void* d_ws, size_t ws_size,
                              hipStream_t stream)
{
    const float* x          = (const float*)d_in[0];
    const float* coef       = (const float*)d_in[1];
    const float* scale_base = (const float*)d_in[2];
    const float* scale_sp   = (const float*)d_in[3];
    const float* bias       = (const float*)d_in[4];
    unsigned short* wt = (unsigned short*)d_ws;   // 4 MB (2 ntiles * 64 kt * 32 KB)
    float* y = (float*)d_out;

    kan_prep<<<1024, 256, 0, stream>>>(coef, scale_base, scale_sp, wt);
    kan_gemm<<<512, 256, 0, stream>>>(x, wt, bias, y);
}